// Round 2
// baseline (471.654 us; speedup 1.0000x reference)
//
#include <hip/hip_runtime.h>
#include <stdint.h>

typedef _Float16 half8 __attribute__((ext_vector_type(8)));
typedef float f32x4 __attribute__((ext_vector_type(4)));

#define CIN   256
#define COUT  256
#define NB    32
#define HH    56
#define WW    56
#define WPAD  58
#define HW2   3136            // 56*56
#define KHALF 4608            // 9 * 256 * 2 (hi/lo interleaved)
#define XQ_BYTES 110231552L   // 32*58*58*256*4
#define WD_BYTES 2359296L     // 256*4608*2

__device__ __forceinline__ float quant_fixed(float x) {
  float q = floorf(x * 65536.0f) * (1.0f / 65536.0f);
  return fminf(fmaxf(q, -32768.0f), 32767.0f);
}

__device__ __forceinline__ void gload16(const void* g, void* l) {
  __builtin_amdgcn_global_load_lds(
      (const __attribute__((address_space(1))) void*)g,
      (__attribute__((address_space(3))) void*)l, 16, 0, 0);
}

// ---------- weight prep: Wd[cout][k], k = r*512 + cin*2 + {hi,lo}, both slots = v ----------
__global__ void prep_w(const float* __restrict__ shift, const float* __restrict__ sgn,
                       uint32_t* __restrict__ Wd32) {
  int idx = blockIdx.x * 256 + threadIdx.x;
  if (idx >= COUT * CIN * 9) return;
  int cout = idx / (CIN * 9);
  int rem  = idx % (CIN * 9);
  int cin  = rem / 9;
  int r    = rem % 9;
  float s  = rintf(fminf(fmaxf(shift[idx], -14.0f), 0.0f));
  float sg = rintf(sgn[idx]);
  float v  = (sg > 0.0f ? 1.0f : (sg < 0.0f ? -1.0f : 0.0f)) * exp2f(s);
  _Float16 vh = (_Float16)v;
  uint16_t u = __builtin_bit_cast(uint16_t, vh);
  Wd32[cout * 2304 + r * 256 + cin] = ((uint32_t)u << 16) | u;
}

// fp32 weights in OIHW order (fallback path only)
__global__ void prep_w_f32(const float* __restrict__ shift, const float* __restrict__ sgn,
                           float* __restrict__ vw) {
  int idx = blockIdx.x * 256 + threadIdx.x;
  if (idx >= COUT * CIN * 9) return;
  float s  = rintf(fminf(fmaxf(shift[idx], -14.0f), 0.0f));
  float sg = rintf(sgn[idx]);
  vw[idx]  = (sg > 0.0f ? 1.0f : (sg < 0.0f ? -1.0f : 0.0f)) * exp2f(s);
}

// ---------- activation prep: NCHW fp32 -> padded NHWC uint32 (lo<<16 | hi fp16 pair) ----------
__global__ void prep_x(const float* __restrict__ in, uint32_t* __restrict__ xq) {
  int cinblk = blockIdx.x;   // 0..3  (64 channels each)
  int h      = blockIdx.y;   // 0..55
  int b      = blockIdx.z;   // 0..31
  int t      = threadIdx.x;  // 256
  __shared__ uint32_t lds[64 * 57];
  const float* src = in + ((long)(b * CIN + cinblk * 64)) * HW2 + h * WW;
  #pragma unroll
  for (int i = 0; i < 14; i++) {           // 64*56 = 3584 = 14*256
    int e = t + i * 256;
    int cin = e / 56, w = e % 56;
    float x = src[(long)cin * HW2 + w];
    float q = quant_fixed(x);
    _Float16 hi = (_Float16)q;
    _Float16 lo = (_Float16)(q - (float)hi);
    uint32_t pk = ((uint32_t)__builtin_bit_cast(uint16_t, lo) << 16)
                 | __builtin_bit_cast(uint16_t, hi);
    lds[cin * 57 + w] = pk;
  }
  __syncthreads();
  uint32_t* dst = xq + ((long)(b * WPAD + h + 1) * WPAD + 1) * CIN + cinblk * 64;
  #pragma unroll
  for (int i = 0; i < 14; i++) {
    int e = t + i * 256;
    int w = e >> 6, cin = e & 63;          // 56*64 layout
    dst[(long)w * CIN + cin] = lds[cin * 57 + w];
  }
}

// zero the 1-pixel halo of xq (228 border cells per batch image)
__global__ void halo_zero(uint32_t* __restrict__ xq) {
  long idx = (long)blockIdx.x * 256 + threadIdx.x;
  if (idx >= (long)NB * 228 * CIN) return;
  int cin = (int)(idx & 255);
  long rem = idx >> 8;
  int b  = (int)(rem / 228);
  int pb = (int)(rem % 228);
  int hp, wp;
  if (pb < 58)       { hp = 0;  wp = pb; }
  else if (pb < 116) { hp = 57; wp = pb - 58; }
  else { int k = pb - 116; hp = 1 + (k >> 1); wp = (k & 1) * 57; }
  xq[(((long)b * WPAD + hp) * WPAD + wp) * CIN + cin] = 0u;
}

__device__ __forceinline__ long pad_off(int p) {   // bytes to x_pad[b][h][w][0] (r=(0,0) tap)
  int b = p / HW2;
  int hw = p % HW2;
  int h = hw / WW;
  int w = hw % WW;
  return ((long)((b * WPAD + h) * WPAD + w)) << 10;  // *256ch*4B
}

// ---------- implicit-GEMM conv: M=cout(128-tile), N=pixels(128-tile), K=4608 halves ----------
// m97 structure: 4 waves, BK=32, global_load_lds width=16, 2 barriers/K-step.
// launch_bounds(256,3): VGPR cap ~170 -> 3 blocks/CU (m97's measured occupancy regime).
__global__ __launch_bounds__(256, 3) void gemm_conv(
    const uint32_t* __restrict__ xq, const uint16_t* __restrict__ Wd,
    const float* __restrict__ bias, float* __restrict__ out) {
  int orig = blockIdx.x;
  int bi = (orig & 7) * 196 + (orig >> 3);   // XCD-bijective swizzle (1568 = 8*196)
  int ct = bi & 1, pt = bi >> 1;
  int cout0 = ct * 128, pix0 = pt * 128;
  int t = threadIdx.x, wv = t >> 6, lane = t & 63;

  __shared__ __align__(1024) char smem[16384];   // As: [0,8K) Bs: [8K,16K)

  int row0 = t >> 2;              // tile row handled by this thread's load (c/4)
  int row1 = row0 + 64;
  int kb   = (t & 3) << 4;        // (c%4)*16 bytes within the 64B K-chunk of a row

  const char* wdc = (const char*)Wd;
  const char* gA0 = wdc + (long)(cout0 + row0) * (KHALF * 2) + kb;
  const char* gA1 = wdc + (long)(cout0 + row1) * (KHALF * 2) + kb;
  const char* xqc = (const char*)xq;
  long pb0 = pad_off(pix0 + row0) + kb;
  long pb1 = pad_off(pix0 + row1) + kb;

  char* AsD0 = smem +         wv * 1024;   // wave-uniform LDS dests (HW adds lane*16)
  char* AsD1 = smem + 4096  + wv * 1024;
  char* BsD0 = smem + 8192  + wv * 1024;
  char* BsD1 = smem + 12288 + wv * 1024;

  int wm = wv >> 1, wn = wv & 1;
  const char* aBase = smem +        (wm * 64 + (lane & 15)) * 64 + (lane >> 4) * 16;
  const char* bBase = smem + 8192 + (wn * 64 + (lane & 15)) * 64 + (lane >> 4) * 16;

  f32x4 acc[4][4] = {};

  #pragma unroll 1
  for (int r = 0; r < 9; r++) {
    long droff = (long)((r / 3) * WPAD + (r % 3)) << 10;
    const char* gB0 = xqc + pb0 + droff;
    const char* gB1 = xqc + pb1 + droff;
    #pragma unroll 1
    for (int t16 = 0; t16 < 16; t16++) {
      gload16(gA0, AsD0);
      gload16(gA1, AsD1);
      gload16(gB0, BsD0);
      gload16(gB1, BsD1);
      gA0 += 64; gA1 += 64; gB0 += 64; gB1 += 64;
      __syncthreads();
      half8 a[4], bf[4];
      #pragma unroll
      for (int i = 0; i < 4; i++) a[i]  = *(const half8*)(aBase + i * 1024);
      #pragma unroll
      for (int j = 0; j < 4; j++) bf[j] = *(const half8*)(bBase + j * 1024);
      #pragma unroll
      for (int i = 0; i < 4; i++)
        #pragma unroll
        for (int j = 0; j < 4; j++)
          acc[i][j] = __builtin_amdgcn_mfma_f32_16x16x32_f16(a[i], bf[j], acc[i][j], 0, 0, 0);
      __syncthreads();
    }
  }

  // epilogue: D row = cout = (lane>>4)*4+reg, col = pixel = lane&15  (m89 layout)
  int rg = (lane >> 4) * 4;
  float bq[4][4];
  #pragma unroll
  for (int i = 0; i < 4; i++)
    #pragma unroll
    for (int q = 0; q < 4; q++) {
      int cg = cout0 + wm * 64 + i * 16 + rg + q;
      bq[i][q] = quant_fixed(bias[cg]);
    }
  #pragma unroll
  for (int j = 0; j < 4; j++) {
    int pg = pix0 + wn * 64 + j * 16 + (lane & 15);
    int b  = pg / HW2;
    int hw = pg % HW2;
    long obase = (long)b * (COUT * HW2) + hw;
    #pragma unroll
    for (int i = 0; i < 4; i++) {
      int cg = cout0 + wm * 64 + i * 16 + rg;
      #pragma unroll
      for (int q = 0; q < 4; q++)
        out[obase + (long)(cg + q) * HW2] = acc[i][j][q] + bq[i][q];
    }
  }
}

// ---------- fallback direct conv (only if workspace too small) ----------
__global__ void conv_direct(const float* __restrict__ in, const float* __restrict__ vw,
                            const float* __restrict__ bias, float* __restrict__ out) {
  long idx = (long)blockIdx.x * 256 + threadIdx.x;
  if (idx >= (long)NB * COUT * HW2) return;
  int hw = (int)(idx % HW2);
  int t2 = (int)(idx / HW2);
  int co = t2 & 255, b = t2 >> 8;
  int h = hw / WW, w = hw % WW;
  float acc = quant_fixed(bias[co]);
  const float* inb = in + (long)b * CIN * HW2;
  const float* vwc = vw + (long)co * CIN * 9;
  for (int ci = 0; ci < CIN; ci++) {
    const float* xp = inb + (long)ci * HW2;
    const float* vp = vwc + ci * 9;
    #pragma unroll
    for (int kh = 0; kh < 3; kh++) {
      int hy = h + kh - 1;
      if ((unsigned)hy >= HH) continue;
      #pragma unroll
      for (int kw = 0; kw < 3; kw++) {
        int wx = w + kw - 1;
        if ((unsigned)wx >= WW) continue;
        acc += quant_fixed(xp[hy * WW + wx]) * vp[kh * 3 + kw];
      }
    }
  }
  out[idx] = acc;
}

extern "C" void kernel_launch(void* const* d_in, const int* in_sizes, int n_in,
                              void* d_out, int out_size, void* d_ws, size_t ws_size,
                              hipStream_t stream) {
  const float* input = (const float*)d_in[0];
  const float* shift = (const float*)d_in[1];
  const float* sgn   = (const float*)d_in[2];
  const float* bias  = (const float*)d_in[3];
  float* out = (float*)d_out;

  if (ws_size >= (size_t)(XQ_BYTES + WD_BYTES)) {
    uint32_t* xq = (uint32_t*)d_ws;
    uint16_t* Wd = (uint16_t*)((char*)d_ws + XQ_BYTES);
    prep_w<<<2304, 256, 0, stream>>>(shift, sgn, (uint32_t*)Wd);
    prep_x<<<dim3(4, 56, 32), 256, 0, stream>>>(input, xq);
    halo_zero<<<7296, 256, 0, stream>>>(xq);
    gemm_conv<<<1568, 256, 0, stream>>>(xq, Wd, bias, out);
  } else {
    float* vw = (float*)d_ws;
    prep_w_f32<<<2304, 256, 0, stream>>>(shift, sgn, vw);
    conv_direct<<<100352, 256, 0, stream>>>(input, vw, bias, out);
  }
}

// Round 3
// 467.743 us; speedup vs baseline: 1.0084x; 1.0084x over previous
//
#include <hip/hip_runtime.h>
#include <stdint.h>

typedef _Float16 half8 __attribute__((ext_vector_type(8)));
typedef float f32x4 __attribute__((ext_vector_type(4)));

#define CIN   256
#define COUT  256
#define NB    32
#define HH    56
#define WW    56
#define WPAD  58
#define HW2   3136            // 56*56
#define KHALF 4608            // 9 * 256 * 2 (hi/lo interleaved)
#define NKT   144             // K-tiles of 32 halves (64B)
#define XQ_BYTES 110231552L   // 32*58*58*256*4
#define WD_BYTES 2359296L     // 256*4608*2

// LDS: 3 A-buffers (256 rows x 64B = 16KB) + 3 B-buffers -> 96KB, 1 block/CU
#define ABUF(i) ((i) * 16384)
#define BBUF(i) (49152 + (i) * 16384)

__device__ __forceinline__ float quant_fixed(float x) {
  float q = floorf(x * 65536.0f) * (1.0f / 65536.0f);
  return fminf(fmaxf(q, -32768.0f), 32767.0f);
}

__device__ __forceinline__ void gload16(const void* g, void* l) {
  __builtin_amdgcn_global_load_lds(
      (const __attribute__((address_space(1))) void*)g,
      (__attribute__((address_space(3))) void*)l, 16, 0, 0);
}

#define WAIT_LGKM0() do { asm volatile("s_waitcnt lgkmcnt(0)" ::: "memory"); \
                          __builtin_amdgcn_sched_barrier(0); } while (0)
#define BAR() __builtin_amdgcn_s_barrier()

// ---------- weight prep: Wd[cout][k], k = r*512 + cin*2 + {hi,lo}, both slots = v ----------
// write-coalesced decomposition (reads gather, writes stream)
__global__ void prep_w(const float* __restrict__ shift, const float* __restrict__ sgn,
                       uint32_t* __restrict__ Wd32) {
  int o = blockIdx.x * 256 + threadIdx.x;       // o = cout*2304 + r*256 + cin
  if (o >= COUT * 2304) return;
  int cout = o / 2304;
  int rem  = o % 2304;
  int r    = rem >> 8;
  int cin  = rem & 255;
  int idx  = cout * 2304 + cin * 9 + r;         // OIHW source index
  float s  = rintf(fminf(fmaxf(shift[idx], -14.0f), 0.0f));
  float sg = rintf(sgn[idx]);
  float v  = (sg > 0.0f ? 1.0f : (sg < 0.0f ? -1.0f : 0.0f)) * exp2f(s);
  _Float16 vh = (_Float16)v;
  uint16_t u = __builtin_bit_cast(uint16_t, vh);
  Wd32[o] = ((uint32_t)u << 16) | u;
}

// fp32 weights in OIHW order (fallback path only)
__global__ void prep_w_f32(const float* __restrict__ shift, const float* __restrict__ sgn,
                           float* __restrict__ vw) {
  int idx = blockIdx.x * 256 + threadIdx.x;
  if (idx >= COUT * CIN * 9) return;
  float s  = rintf(fminf(fmaxf(shift[idx], -14.0f), 0.0f));
  float sg = rintf(sgn[idx]);
  vw[idx]  = (sg > 0.0f ? 1.0f : (sg < 0.0f ? -1.0f : 0.0f)) * exp2f(s);
}

// ---------- activation prep: NCHW fp32 -> padded NHWC uint32 (lo<<16 | hi fp16 pair) ----------
__global__ void prep_x(const float* __restrict__ in, uint32_t* __restrict__ xq) {
  int cinblk = blockIdx.x;   // 0..3  (64 channels each)
  int h      = blockIdx.y;   // 0..55
  int b      = blockIdx.z;   // 0..31
  int t      = threadIdx.x;  // 256
  __shared__ uint32_t lds[64 * 57];
  const float* src = in + ((long)(b * CIN + cinblk * 64)) * HW2 + h * WW;
  #pragma unroll
  for (int i = 0; i < 14; i++) {           // 64*56 = 3584 = 14*256
    int e = t + i * 256;
    int cin = e / 56, w = e % 56;
    float x = src[(long)cin * HW2 + w];
    float q = quant_fixed(x);
    _Float16 hi = (_Float16)q;
    _Float16 lo = (_Float16)(q - (float)hi);
    uint32_t pk = ((uint32_t)__builtin_bit_cast(uint16_t, lo) << 16)
                 | __builtin_bit_cast(uint16_t, hi);
    lds[cin * 57 + w] = pk;
  }
  __syncthreads();
  uint32_t* dst = xq + ((long)(b * WPAD + h + 1) * WPAD + 1) * CIN + cinblk * 64;
  #pragma unroll
  for (int i = 0; i < 14; i++) {
    int e = t + i * 256;
    int w = e >> 6, cin = e & 63;          // 56*64 layout
    dst[(long)w * CIN + cin] = lds[cin * 57 + w];
  }
}

// zero the 1-pixel halo of xq (228 border cells per batch image)
__global__ void halo_zero(uint32_t* __restrict__ xq) {
  long idx = (long)blockIdx.x * 256 + threadIdx.x;
  if (idx >= (long)NB * 228 * CIN) return;
  int cin = (int)(idx & 255);
  long rem = idx >> 8;
  int b  = (int)(rem / 228);
  int pb = (int)(rem % 228);
  int hp, wp;
  if (pb < 58)       { hp = 0;  wp = pb; }
  else if (pb < 116) { hp = 57; wp = pb - 58; }
  else { int k = pb - 116; hp = 1 + (k >> 1); wp = (k & 1) * 57; }
  xq[(((long)b * WPAD + hp) * WPAD + wp) * CIN + cin] = 0u;
}

__device__ __forceinline__ long pad_off(int p) {   // bytes to x_pad[b][h][w][0] (r=(0,0) tap)
  int b = p / HW2;
  int hw = p % HW2;
  int h = hw / WW;
  int w = hw % WW;
  return ((long)((b * WPAD + h) * WPAD + w)) << 10;  // *256ch*4B
}

// stage one full K-tile (A0,A1,B0,B1 halves) — prologue only
template<int SB>
__device__ __forceinline__ void stage4(char* smem, int wv,
    const char* sA0, const char* sA1, const char* sB0, const char* sB1) {
  gload16(sA0, smem + ABUF(SB) + wv * 1024);
  gload16(sA1, smem + ABUF(SB) + 8192 + wv * 1024);
  gload16(sB0, smem + BBUF(SB) + wv * 1024);
  gload16(sB1, smem + BBUF(SB) + 8192 + wv * 1024);
}

// One K-tile (BK=32 halves): 2 phases x 16 MFMA. Reads buf RB, stages tile kt+2
// into buf SB (A halves in phase 0, B halves in phase 1). ENDW: counted vmcnt at
// tile end (4 = keep kt+2's stages in flight; 0 = drain; -1 = none).
template<int RB, int SB, int STG, int ENDW>
__device__ __forceinline__ void tile_step(char* smem, int wv, int aoff, int boff,
    const char* sA0, const char* sA1, const char* sB0, const char* sB1,
    f32x4 (&acc)[8][4]) {
  const char* Ab = smem + ABUF(RB) + aoff;
  const char* Bb = smem + BBUF(RB) + boff;
  half8 bf[4], af[4];
  // ---- phase 0: m-half 0 ----
  #pragma unroll
  for (int nf = 0; nf < 4; ++nf) bf[nf] = *(const half8*)(Bb + nf * 1024);
  #pragma unroll
  for (int j = 0; j < 4; ++j) af[j] = *(const half8*)(Ab + j * 1024);
  if (STG) {
    gload16(sA0, smem + ABUF(SB) + wv * 1024);
    gload16(sA1, smem + ABUF(SB) + 8192 + wv * 1024);
  }
  BAR();
  WAIT_LGKM0();
  __builtin_amdgcn_s_setprio(1);
  #pragma unroll
  for (int j = 0; j < 4; ++j)
    #pragma unroll
    for (int nf = 0; nf < 4; ++nf)
      acc[j][nf] = __builtin_amdgcn_mfma_f32_16x16x32_f16(af[j], bf[nf], acc[j][nf], 0, 0, 0);
  __builtin_amdgcn_s_setprio(0);
  BAR();
  // ---- phase 1: m-half 1 ----
  #pragma unroll
  for (int j = 0; j < 4; ++j) af[j] = *(const half8*)(Ab + 4096 + j * 1024);
  if (STG) {
    gload16(sB0, smem + BBUF(SB) + wv * 1024);
    gload16(sB1, smem + BBUF(SB) + 8192 + wv * 1024);
  }
  BAR();
  WAIT_LGKM0();
  __builtin_amdgcn_s_setprio(1);
  #pragma unroll
  for (int j = 0; j < 4; ++j)
    #pragma unroll
    for (int nf = 0; nf < 4; ++nf)
      acc[4 + j][nf] = __builtin_amdgcn_mfma_f32_16x16x32_f16(af[j], bf[nf], acc[4 + j][nf], 0, 0, 0);
  __builtin_amdgcn_s_setprio(0);
  if constexpr (ENDW == 4) {
    asm volatile("s_waitcnt vmcnt(4)" ::: "memory");
    __builtin_amdgcn_sched_barrier(0);
  } else if constexpr (ENDW == 0) {
    asm volatile("s_waitcnt vmcnt(0)" ::: "memory");
    __builtin_amdgcn_sched_barrier(0);
  }
  BAR();
}

// ---------- implicit-GEMM conv: 256(cout) x 256(pix) tile, 8 waves, 3-buf depth-2 pipeline ----------
__global__ __launch_bounds__(512, 2) void gemm_conv(
    const uint32_t* __restrict__ xq, const uint16_t* __restrict__ Wd,
    const float* __restrict__ bias, float* __restrict__ out) {
  int orig = blockIdx.x;                       // 392 = 8 * 49
  int bi = (orig & 7) * 49 + (orig >> 3);      // XCD-bijective swizzle
  int pix0 = bi << 8;
  int t = threadIdx.x, wv = t >> 6, lane = t & 63;
  int wm = wv >> 2, wn = wv & 3;               // wave grid 2(M) x 4(N)

  __shared__ __align__(1024) char smem[98304];

  // staging addresses (per-lane global sources; LDS dest = wave-uniform + lane*16)
  int srow = wv * 16 + (lane >> 2);
  int sb   = (lane & 3) * 16;
  const char* wdc = (const char*)Wd;
  const char* xqc = (const char*)xq;
  const char* sA0 = wdc + (long)srow * 9216 + sb;            // cout rows 0..127
  const char* sA1 = wdc + (long)(srow + 128) * 9216 + sb;    // cout rows 128..255
  const char* sB0 = xqc + pad_off(pix0 + srow) + sb;         // pixel rows 0..127
  const char* sB1 = xqc + pad_off(pix0 + srow + 128) + sb;   // pixel rows 128..255

  // fragment read offsets (64B rows -> naturally bank-conflict-free b128 reads)
  int aoff = (wm * 128 + (lane & 15)) * 64 + (lane >> 4) * 16;
  int boff = (wn * 64 + (lane & 15)) * 64 + (lane >> 4) * 16;

  f32x4 acc[8][4] = {};

  int st = 0;  // tiles staged so far; B makes a row jump entering tap-rows 1,2
  auto step = [&]() {
    sA0 += 64; sA1 += 64; sB0 += 64; sB1 += 64; ++st;
    if (st == 48 || st == 96) { sB0 += 56320; sB1 += 56320; }  // 58*1024 - 48*64
  };

  // prologue: stage tiles 0,1; wait tile 0 landed (keep tile 1's 4 loads in flight)
  stage4<0>(smem, wv, sA0, sA1, sB0, sB1); step();
  stage4<1>(smem, wv, sA0, sA1, sB0, sB1); step();
  asm volatile("s_waitcnt vmcnt(4)" ::: "memory");
  __builtin_amdgcn_sched_barrier(0);
  BAR();

  // main loop: 141 tiles (47 x 3 for static buffer rotation), then peel 141..143
  #pragma unroll 1
  for (int it = 0; it < 47; ++it) {
    tile_step<0, 2, 1, 4>(smem, wv, aoff, boff, sA0, sA1, sB0, sB1, acc); step();
    tile_step<1, 0, 1, 4>(smem, wv, aoff, boff, sA0, sA1, sB0, sB1, acc); step();
    tile_step<2, 1, 1, 4>(smem, wv, aoff, boff, sA0, sA1, sB0, sB1, acc); step();
  }
  tile_step<0, 2, 1, 4>(smem, wv, aoff, boff, sA0, sA1, sB0, sB1, acc); step();  // kt=141
  tile_step<1, 0, 0, 0>(smem, wv, aoff, boff, sA0, sA1, sB0, sB1, acc);          // kt=142
  tile_step<2, 0, 0, -1>(smem, wv, aoff, boff, sA0, sA1, sB0, sB1, acc);         // kt=143

  // epilogue: D row = cout = wm*128 + mf*16 + (lane>>4)*4 + r2, col = pixel (m89 layout)
  int rg4  = (lane >> 4) * 4;
  int colp = lane & 15;
  float bq[8][4];
  #pragma unroll
  for (int mf = 0; mf < 8; ++mf) {
    f32x4 bv = *(const f32x4*)(bias + wm * 128 + mf * 16 + rg4);
    #pragma unroll
    for (int r2 = 0; r2 < 4; ++r2) bq[mf][r2] = quant_fixed(bv[r2]);
  }
  #pragma unroll
  for (int nf = 0; nf < 4; ++nf) {
    int pg = pix0 + wn * 64 + nf * 16 + colp;
    int b  = pg / HW2;
    int hw = pg % HW2;
    long ob = (long)b * (COUT * HW2) + hw;
    #pragma unroll
    for (int mf = 0; mf < 8; ++mf) {
      int cg = wm * 128 + mf * 16 + rg4;
      #pragma unroll
      for (int r2 = 0; r2 < 4; ++r2)
        out[ob + (long)(cg + r2) * HW2] = acc[mf][nf][r2] + bq[mf][r2];
    }
  }
}

// ---------- fallback direct conv (only if workspace too small) ----------
__global__ void conv_direct(const float* __restrict__ in, const float* __restrict__ vw,
                            const float* __restrict__ bias, float* __restrict__ out) {
  long idx = (long)blockIdx.x * 256 + threadIdx.x;
  if (idx >= (long)NB * COUT * HW2) return;
  int hw = (int)(idx % HW2);
  int t2 = (int)(idx / HW2);
  int co = t2 & 255, b = t2 >> 8;
  int h = hw / WW, w = hw % WW;
  float acc = quant_fixed(bias[co]);
  const float* inb = in + (long)b * CIN * HW2;
  const float* vwc = vw + (long)co * CIN * 9;
  for (int ci = 0; ci < CIN; ci++) {
    const float* xp = inb + (long)ci * HW2;
    const float* vp = vwc + ci * 9;
    #pragma unroll
    for (int kh = 0; kh < 3; kh++) {
      int hy = h + kh - 1;
      if ((unsigned)hy >= HH) continue;
      #pragma unroll
      for (int kw = 0; kw < 3; kw++) {
        int wx = w + kw - 1;
        if ((unsigned)wx >= WW) continue;
        acc += quant_fixed(xp[hy * WW + wx]) * vp[kh * 3 + kw];
      }
    }
  }
  out[idx] = acc;
}

extern "C" void kernel_launch(void* const* d_in, const int* in_sizes, int n_in,
                              void* d_out, int out_size, void* d_ws, size_t ws_size,
                              hipStream_t stream) {
  const float* input = (const float*)d_in[0];
  const float* shift = (const float*)d_in[1];
  const float* sgn   = (const float*)d_in[2];
  const float* bias  = (const float*)d_in[3];
  float* out = (float*)d_out;

  if (ws_size >= (size_t)(XQ_BYTES + WD_BYTES)) {
    uint32_t* xq = (uint32_t*)d_ws;
    uint16_t* Wd = (uint16_t*)((char*)d_ws + XQ_BYTES);
    prep_w<<<2304, 256, 0, stream>>>(shift, sgn, (uint32_t*)Wd);
    prep_x<<<dim3(4, 56, 32), 256, 0, stream>>>(input, xq);
    halo_zero<<<7296, 256, 0, stream>>>(xq);
    gemm_conv<<<392, 512, 0, stream>>>(xq, Wd, bias, out);
  } else {
    float* vw = (float*)d_ws;
    prep_w_f32<<<2304, 256, 0, stream>>>(shift, sgn, vw);
    conv_direct<<<100352, 256, 0, stream>>>(input, vw, bias, out);
  }
}

// Round 5
// 443.092 us; speedup vs baseline: 1.0645x; 1.0556x over previous
//
#include <hip/hip_runtime.h>
#include <stdint.h>

typedef _Float16 half8 __attribute__((ext_vector_type(8)));
typedef float f32x4 __attribute__((ext_vector_type(4)));

#define CIN   256
#define COUT  256
#define NB    32
#define HH    56
#define WW    56
#define WPAD  58
#define HW2   3136            // 56*56
#define KHALF 4608            // 9 * 256 * 2 (hi/lo interleaved)
#define NKT   144             // K-tiles of 32 halves (64B)
#define XQ_BYTES 110231552L   // 32*58*58*256*4
#define WD_BYTES 2359296L     // 256*4608*2

// LDS: 3 A-buffers (256 rows x 64B = 16KB) + 3 B-buffers -> 96KB, 1 block/CU
#define ABUF(i) ((i) * 16384)
#define BBUF(i) (49152 + (i) * 16384)

__device__ __forceinline__ float quant_fixed(float x) {
  float q = floorf(x * 65536.0f) * (1.0f / 65536.0f);
  return fminf(fmaxf(q, -32768.0f), 32767.0f);
}

__device__ __forceinline__ void gload16(const void* g, void* l) {
  __builtin_amdgcn_global_load_lds(
      (const __attribute__((address_space(1))) void*)g,
      (__attribute__((address_space(3))) void*)l, 16, 0, 0);
}

#define WAIT_LGKM0() do { asm volatile("s_waitcnt lgkmcnt(0)" ::: "memory"); \
                          __builtin_amdgcn_sched_barrier(0); } while (0)
#define BAR() __builtin_amdgcn_s_barrier()

// ---------- weight prep: Wd[cout][k], k = r*512 + cin*2 + {hi,lo}, both slots = v ----------
__global__ void prep_w(const float* __restrict__ shift, const float* __restrict__ sgn,
                       uint32_t* __restrict__ Wd32) {
  int o = blockIdx.x * 256 + threadIdx.x;       // o = cout*2304 + r*256 + cin
  if (o >= COUT * 2304) return;
  int cout = o / 2304;
  int rem  = o % 2304;
  int r    = rem >> 8;
  int cin  = rem & 255;
  int idx  = cout * 2304 + cin * 9 + r;         // OIHW source index
  float s  = rintf(fminf(fmaxf(shift[idx], -14.0f), 0.0f));
  float sg = rintf(sgn[idx]);
  float v  = (sg > 0.0f ? 1.0f : (sg < 0.0f ? -1.0f : 0.0f)) * exp2f(s);
  _Float16 vh = (_Float16)v;
  uint16_t u = __builtin_bit_cast(uint16_t, vh);
  Wd32[o] = ((uint32_t)u << 16) | u;
}

// fp32 weights in OIHW order (fallback path only)
__global__ void prep_w_f32(const float* __restrict__ shift, const float* __restrict__ sgn,
                           float* __restrict__ vw) {
  int idx = blockIdx.x * 256 + threadIdx.x;
  if (idx >= COUT * CIN * 9) return;
  float s  = rintf(fminf(fmaxf(shift[idx], -14.0f), 0.0f));
  float sg = rintf(sgn[idx]);
  vw[idx]  = (sg > 0.0f ? 1.0f : (sg < 0.0f ? -1.0f : 0.0f)) * exp2f(s);
}

// ---------- activation prep: NCHW fp32 -> padded NHWC uint32 (lo<<16 | hi fp16 pair) ----------
__global__ void prep_x(const float* __restrict__ in, uint32_t* __restrict__ xq) {
  int cinblk = blockIdx.x;   // 0..3  (64 channels each)
  int h      = blockIdx.y;   // 0..55
  int b      = blockIdx.z;   // 0..31
  int t      = threadIdx.x;  // 256
  __shared__ uint32_t lds[64 * 57];
  const float* src = in + ((long)(b * CIN + cinblk * 64)) * HW2 + h * WW;
  #pragma unroll
  for (int i = 0; i < 14; i++) {           // 64*56 = 3584 = 14*256
    int e = t + i * 256;
    int cin = e / 56, w = e % 56;
    float x = src[(long)cin * HW2 + w];
    float q = quant_fixed(x);
    _Float16 hi = (_Float16)q;
    _Float16 lo = (_Float16)(q - (float)hi);
    uint32_t pk = ((uint32_t)__builtin_bit_cast(uint16_t, lo) << 16)
                 | __builtin_bit_cast(uint16_t, hi);
    lds[cin * 57 + w] = pk;
  }
  __syncthreads();
  uint32_t* dst = xq + ((long)(b * WPAD + h + 1) * WPAD + 1) * CIN + cinblk * 64;
  #pragma unroll
  for (int i = 0; i < 14; i++) {
    int e = t + i * 256;
    int w = e >> 6, cin = e & 63;          // 56*64 layout
    dst[(long)w * CIN + cin] = lds[cin * 57 + w];
  }
}

// zero the 1-pixel halo of xq (228 border cells per batch image)
__global__ void halo_zero(uint32_t* __restrict__ xq) {
  long idx = (long)blockIdx.x * 256 + threadIdx.x;
  if (idx >= (long)NB * 228 * CIN) return;
  int cin = (int)(idx & 255);
  long rem = idx >> 8;
  int b  = (int)(rem / 228);
  int pb = (int)(rem % 228);
  int hp, wp;
  if (pb < 58)       { hp = 0;  wp = pb; }
  else if (pb < 116) { hp = 57; wp = pb - 58; }
  else { int k = pb - 116; hp = 1 + (k >> 1); wp = (k & 1) * 57; }
  xq[(((long)b * WPAD + hp) * WPAD + wp) * CIN + cin] = 0u;
}

__device__ __forceinline__ long pad_off(int p) {   // bytes to x_pad[b][h][w][0] (r=(0,0) tap)
  int b = p / HW2;
  int hw = p % HW2;
  int h = hw / WW;
  int w = hw % WW;
  return ((long)((b * WPAD + h) * WPAD + w)) << 10;  // *256ch*4B
}

// stage one full K-tile (A0,A1,B0,B1 halves) — prologue only
template<int SB>
__device__ __forceinline__ void stage4(char* smem, int wv,
    const char* sA0, const char* sA1, const char* sB0, const char* sB1) {
  gload16(sA0, smem + ABUF(SB) + wv * 1024);
  gload16(sA1, smem + ABUF(SB) + 8192 + wv * 1024);
  gload16(sB0, smem + BBUF(SB) + wv * 1024);
  gload16(sB1, smem + BBUF(SB) + 8192 + wv * 1024);
}

// One K-tile (BK=32 halves): 2 phases x 16 MFMA. Reads buf RB, stages tile kt+2
// into buf SB (A halves in phase 0, B halves in phase 1). ENDW: counted vmcnt at
// tile end (4 = keep kt+2's stages in flight; 0 = drain; -1 = none).
template<int RB, int SB, int STG, int ENDW>
__device__ __forceinline__ void tile_step(char* smem, int wv, int aoff, int boff,
    const char* sA0, const char* sA1, const char* sB0, const char* sB1,
    f32x4 (&acc)[8][4]) {
  const char* Ab = smem + ABUF(RB) + aoff;
  const char* Bb = smem + BBUF(RB) + boff;
  half8 bf[4], af[4];
  // ---- phase 0: m-half 0 ----
  #pragma unroll
  for (int nf = 0; nf < 4; ++nf) bf[nf] = *(const half8*)(Bb + nf * 1024);
  #pragma unroll
  for (int j = 0; j < 4; ++j) af[j] = *(const half8*)(Ab + j * 1024);
  if (STG) {
    gload16(sA0, smem + ABUF(SB) + wv * 1024);
    gload16(sA1, smem + ABUF(SB) + 8192 + wv * 1024);
  }
  BAR();
  WAIT_LGKM0();
  __builtin_amdgcn_s_setprio(1);
  #pragma unroll
  for (int j = 0; j < 4; ++j)
    #pragma unroll
    for (int nf = 0; nf < 4; ++nf)
      acc[j][nf] = __builtin_amdgcn_mfma_f32_16x16x32_f16(af[j], bf[nf], acc[j][nf], 0, 0, 0);
  __builtin_amdgcn_s_setprio(0);
  BAR();
  // ---- phase 1: m-half 1 ----
  #pragma unroll
  for (int j = 0; j < 4; ++j) af[j] = *(const half8*)(Ab + 4096 + j * 1024);
  if (STG) {
    gload16(sB0, smem + BBUF(SB) + wv * 1024);
    gload16(sB1, smem + BBUF(SB) + 8192 + wv * 1024);
  }
  BAR();
  WAIT_LGKM0();
  __builtin_amdgcn_s_setprio(1);
  #pragma unroll
  for (int j = 0; j < 4; ++j)
    #pragma unroll
    for (int nf = 0; nf < 4; ++nf)
      acc[4 + j][nf] = __builtin_amdgcn_mfma_f32_16x16x32_f16(af[j], bf[nf], acc[4 + j][nf], 0, 0, 0);
  __builtin_amdgcn_s_setprio(0);
  if constexpr (ENDW == 4) {
    asm volatile("s_waitcnt vmcnt(4)" ::: "memory");
    __builtin_amdgcn_sched_barrier(0);
  } else if constexpr (ENDW == 0) {
    asm volatile("s_waitcnt vmcnt(0)" ::: "memory");
    __builtin_amdgcn_sched_barrier(0);
  }
  BAR();
}

// ---------- implicit-GEMM conv: 256(cout) x 256(pix) tile, 8 waves, 3-buf depth-2 pipeline ----------
// T2 (adapted): K-chunk XOR swizzle. gload_lds writes linearly, so the swizzle is applied by
// pre-swizzling the per-lane GLOBAL source chunk (same 64B line): LDS slot c of row r holds
// logical chunk c ^ ((r>>1)&3). Reads compensate. Bank-group g = 4(r&1) + slot -> 8 distinct
// groups over 8 consecutive rows => 2-way (b128 floor) instead of the old 8-way conflict.
__global__ __launch_bounds__(512, 2) void gemm_conv(
    const uint32_t* __restrict__ xq, const uint16_t* __restrict__ Wd,
    const float* __restrict__ bias, float* __restrict__ out) {
  int orig = blockIdx.x;                       // 392 = 8 * 49
  int bi = (orig & 7) * 49 + (orig >> 3);      // XCD-bijective swizzle
  int pix0 = bi << 8;
  int t = threadIdx.x, wv = t >> 6, lane = t & 63;
  int wm = wv >> 2, wn = wv & 3;               // wave grid 2(M) x 4(N)

  __shared__ __align__(1024) char smem[98304];

  // staging: lane l stages global chunk (l&3)^((l>>3)&3) of row wv*16+(l>>2)
  // into LDS linear slot l&3  => LDS slot c holds logical chunk c^((row>>1)&3)
  int srow = wv * 16 + (lane >> 2);
  int sb   = (((lane & 3) ^ ((lane >> 3) & 3)) * 16);
  const char* wdc = (const char*)Wd;
  const char* xqc = (const char*)xq;
  const char* sA0 = wdc + (long)srow * 9216 + sb;            // cout rows 0..127
  const char* sA1 = wdc + (long)(srow + 128) * 9216 + sb;    // cout rows 128..255
  const char* sB0 = xqc + pad_off(pix0 + srow) + sb;         // pixel rows 0..127
  const char* sB1 = xqc + pad_off(pix0 + srow + 128) + sb;   // pixel rows 128..255

  // fragment reads: logical k-chunk s=lane>>4 lives at slot s^(((lane&15)>>1)&3)
  // (row bases are multiples of 16, so the XOR term depends only on lane&15)
  int r15  = lane & 15;
  int slot = (lane >> 4) ^ ((r15 >> 1) & 3);
  int aoff = (wm * 128 + r15) * 64 + slot * 16;
  int boff = (wn * 64 + r15) * 64 + slot * 16;

  f32x4 acc[8][4] = {};

  int st = 0;  // tiles staged so far; B makes a row jump entering tap-rows 1,2
  auto step = [&]() {
    sA0 += 64; sA1 += 64; sB0 += 64; sB1 += 64; ++st;
    if (st == 48 || st == 96) { sB0 += 56320; sB1 += 56320; }  // 58*1024 - 48*64
  };

  // prologue: stage tiles 0,1; wait tile 0 landed (keep tile 1's 4 loads in flight)
  stage4<0>(smem, wv, sA0, sA1, sB0, sB1); step();
  stage4<1>(smem, wv, sA0, sA1, sB0, sB1); step();
  asm volatile("s_waitcnt vmcnt(4)" ::: "memory");
  __builtin_amdgcn_sched_barrier(0);
  BAR();

  // main loop: 141 tiles (47 x 3 for static buffer rotation), then peel 141..143
  #pragma unroll 1
  for (int it = 0; it < 47; ++it) {
    tile_step<0, 2, 1, 4>(smem, wv, aoff, boff, sA0, sA1, sB0, sB1, acc); step();
    tile_step<1, 0, 1, 4>(smem, wv, aoff, boff, sA0, sA1, sB0, sB1, acc); step();
    tile_step<2, 1, 1, 4>(smem, wv, aoff, boff, sA0, sA1, sB0, sB1, acc); step();
  }
  tile_step<0, 2, 1, 4>(smem, wv, aoff, boff, sA0, sA1, sB0, sB1, acc); step();  // kt=141
  tile_step<1, 0, 0, 0>(smem, wv, aoff, boff, sA0, sA1, sB0, sB1, acc);          // kt=142
  tile_step<2, 0, 0, -1>(smem, wv, aoff, boff, sA0, sA1, sB0, sB1, acc);         // kt=143

  // epilogue: D row = cout = wm*128 + mf*16 + (lane>>4)*4 + r2, col = pixel (m89 layout)
  int rg4  = (lane >> 4) * 4;
  int colp = lane & 15;
  float bq[8][4];
  #pragma unroll
  for (int mf = 0; mf < 8; ++mf) {
    f32x4 bv = *(const f32x4*)(bias + wm * 128 + mf * 16 + rg4);
    #pragma unroll
    for (int r2 = 0; r2 < 4; ++r2) bq[mf][r2] = quant_fixed(bv[r2]);
  }
  #pragma unroll
  for (int nf = 0; nf < 4; ++nf) {
    int pg = pix0 + wn * 64 + nf * 16 + colp;
    int b  = pg / HW2;
    int hw = pg % HW2;
    long ob = (long)b * (COUT * HW2) + hw;
    #pragma unroll
    for (int mf = 0; mf < 8; ++mf) {
      int cg = wm * 128 + mf * 16 + rg4;
      #pragma unroll
      for (int r2 = 0; r2 < 4; ++r2)
        out[ob + (long)(cg + r2) * HW2] = acc[mf][nf][r2] + bq[mf][r2];
    }
  }
}

// ---------- fallback direct conv (only if workspace too small) ----------
__global__ void conv_direct(const float* __restrict__ in, const float* __restrict__ vw,
                            const float* __restrict__ bias, float* __restrict__ out) {
  long idx = (long)blockIdx.x * 256 + threadIdx.x;
  if (idx >= (long)NB * COUT * HW2) return;
  int hw = (int)(idx % HW2);
  int t2 = (int)(idx / HW2);
  int co = t2 & 255, b = t2 >> 8;
  int h = hw / WW, w = hw % WW;
  float acc = quant_fixed(bias[co]);
  const float* inb = in + (long)b * CIN * HW2;
  const float* vwc = vw + (long)co * CIN * 9;
  for (int ci = 0; ci < CIN; ci++) {
    const float* xp = inb + (long)ci * HW2;
    const float* vp = vwc + ci * 9;
    #pragma unroll
    for (int kh = 0; kh < 3; kh++) {
      int hy = h + kh - 1;
      if ((unsigned)hy >= HH) continue;
      #pragma unroll
      for (int kw = 0; kw < 3; kw++) {
        int wx = w + kw - 1;
        if ((unsigned)wx >= WW) continue;
        acc += quant_fixed(xp[hy * WW + wx]) * vp[kh * 3 + kw];
      }
    }
  }
  out[idx] = acc;
}

extern "C" void kernel_launch(void* const* d_in, const int* in_sizes, int n_in,
                              void* d_out, int out_size, void* d_ws, size_t ws_size,
                              hipStream_t stream) {
  const float* input = (const float*)d_in[0];
  const float* shift = (const float*)d_in[1];
  const float* sgn   = (const float*)d_in[2];
  const float* bias  = (const float*)d_in[3];
  float* out = (float*)d_out;

  if (ws_size >= (size_t)(XQ_BYTES + WD_BYTES)) {
    uint32_t* xq = (uint32_t*)d_ws;
    uint16_t* Wd = (uint16_t*)((char*)d_ws + XQ_BYTES);
    prep_w<<<2304, 256, 0, stream>>>(shift, sgn, (uint32_t*)Wd);
    prep_x<<<dim3(4, 56, 32), 256, 0, stream>>>(input, xq);
    halo_zero<<<7296, 256, 0, stream>>>(xq);
    gemm_conv<<<392, 512, 0, stream>>>(xq, Wd, bias, out);
  } else {
    float* vw = (float*)d_ws;
    prep_w_f32<<<2304, 256, 0, stream>>>(shift, sgn, vw);
    conv_direct<<<100352, 256, 0, stream>>>(input, vw, bias, out);
  }
}